// Round 1
// baseline (3232.783 us; speedup 1.0000x reference)
//
#include <hip/hip_runtime.h>
#include <math.h>

#define BATCH 2
#define SEQ 2048
#define DMODEL 2048
#define NH 16
#define HD 128
#define QB 32
#define KB 32

// =====================================================================
// GEMM (NT): C[M,N] = A[M,K] . B[N,K]^T   (dot of A-rows with B-rows)
// 128x128 block tile, BK=16, 256 threads, 8x8 per-thread register tile.
// LDS staged transposed As[k][m] so inner loop does float4 reads.
// =====================================================================
__global__ __launch_bounds__(256) void gemm_nt(const float* __restrict__ A,
                                               const float* __restrict__ B,
                                               float* __restrict__ C,
                                               int M, int N, int K) {
    __shared__ float As[16][132];   // [BK][BM+4] pad -> 16B-aligned rows, low conflicts
    __shared__ float Bs[16][132];

    const int tid = threadIdx.x;
    const int tx = tid & 15;
    const int ty = tid >> 4;
    const int m0 = blockIdx.y * 128;
    const int n0 = blockIdx.x * 128;

    const int lrow = tid >> 2;          // 0..63
    const int lc4  = (tid & 3) << 2;    // 0,4,8,12

    const float* Ap = A + (size_t)(m0 + lrow) * K + lc4;
    const float* Bp = B + (size_t)(n0 + lrow) * K + lc4;

    float acc[8][8];
#pragma unroll
    for (int i = 0; i < 8; ++i)
#pragma unroll
        for (int j = 0; j < 8; ++j) acc[i][j] = 0.f;

    for (int k0 = 0; k0 < K; k0 += 16) {
        // issue global loads before the barrier so they overlap prior compute
        float4 a0 = *(const float4*)(Ap);
        float4 a1 = *(const float4*)(Ap + (size_t)64 * K);
        float4 b0 = *(const float4*)(Bp);
        float4 b1 = *(const float4*)(Bp + (size_t)64 * K);
        Ap += 16; Bp += 16;

        __syncthreads();   // previous iteration finished reading LDS
        As[lc4 + 0][lrow] = a0.x;  As[lc4 + 1][lrow] = a0.y;
        As[lc4 + 2][lrow] = a0.z;  As[lc4 + 3][lrow] = a0.w;
        As[lc4 + 0][64 + lrow] = a1.x;  As[lc4 + 1][64 + lrow] = a1.y;
        As[lc4 + 2][64 + lrow] = a1.z;  As[lc4 + 3][64 + lrow] = a1.w;
        Bs[lc4 + 0][lrow] = b0.x;  Bs[lc4 + 1][lrow] = b0.y;
        Bs[lc4 + 2][lrow] = b0.z;  Bs[lc4 + 3][lrow] = b0.w;
        Bs[lc4 + 0][64 + lrow] = b1.x;  Bs[lc4 + 1][64 + lrow] = b1.y;
        Bs[lc4 + 2][64 + lrow] = b1.z;  Bs[lc4 + 3][64 + lrow] = b1.w;
        __syncthreads();

#pragma unroll
        for (int kk = 0; kk < 16; ++kk) {
            float4 A0 = *(const float4*)&As[kk][4 * ty];
            float4 A1 = *(const float4*)&As[kk][64 + 4 * ty];
            float4 B0 = *(const float4*)&Bs[kk][4 * tx];
            float4 B1 = *(const float4*)&Bs[kk][64 + 4 * tx];
            float ar[8] = {A0.x, A0.y, A0.z, A0.w, A1.x, A1.y, A1.z, A1.w};
            float br[8] = {B0.x, B0.y, B0.z, B0.w, B1.x, B1.y, B1.z, B1.w};
#pragma unroll
            for (int i = 0; i < 8; ++i)
#pragma unroll
                for (int j = 0; j < 8; ++j) acc[i][j] += ar[i] * br[j];
        }
    }

#pragma unroll
    for (int i = 0; i < 8; ++i) {
        const int m = m0 + ((i < 4) ? (4 * ty + i) : (64 + 4 * ty + (i - 4)));
        float4 v0 = make_float4(acc[i][0], acc[i][1], acc[i][2], acc[i][3]);
        float4 v1 = make_float4(acc[i][4], acc[i][5], acc[i][6], acc[i][7]);
        *(float4*)&C[(size_t)m * N + n0 + 4 * tx] = v0;
        *(float4*)&C[(size_t)m * N + n0 + 64 + 4 * tx] = v1;
    }
}

// =====================================================================
// RoPE (in-place on Q and K, layout (b, s, h*hd)); one thread per pair.
// =====================================================================
__global__ __launch_bounds__(256) void rope_kernel(float* __restrict__ q,
                                                   float* __restrict__ k,
                                                   const float* __restrict__ cosp,
                                                   const float* __restrict__ sinp) {
    const long long pi = (long long)blockIdx.x * 256 + threadIdx.x;
    float* t = blockIdx.y ? k : q;
    const long long flat = pi * 2;
    const int s = (int)((flat / DMODEL) % SEQ);
    const int c = (int)(flat % DMODEL);
    const int p = (c % HD) >> 1;
    float2 v = *(float2*)&t[flat];
    const float cs = cosp[s * (HD / 2) + p];
    const float sn = sinp[s * (HD / 2) + p];
    float2 o;
    o.x = v.x * cs - v.y * sn;
    o.y = v.x * sn + v.y * cs;
    *(float2*)&t[flat] = o;
}

// =====================================================================
// Flash attention, fp32, causal. QB=KB=32, 256 threads.
// Each thread: 2x2 score tile (rows 2*ty+{0,1}, cols 2*tx+{0,1}),
// PV accumulator 2 rows x 8 cols (cols 4*tx+{0..3} and 64+4*tx+{0..3}).
// Static LDS total = 54.1 KB -> 2 blocks/CU.
// o may alias q: each block reads exactly its own q-slice into LDS at
// start and writes o to those same addresses only at the very end.
// =====================================================================
__global__ __launch_bounds__(256) void attn_kernel(const float* q,
                                                   const float* __restrict__ k,
                                                   const float* __restrict__ v,
                                                   float* o) {
    __shared__ float Qs[QB][129];
    __shared__ float Ks[KB][129];
    __shared__ float Vs[KB][132];
    __shared__ float Ps[QB][KB + 1];

    const int tid = threadIdx.x;
    const int tx = tid & 15;
    const int ty = tid >> 4;
    const int b = blockIdx.z;
    const int h = blockIdx.y;
    const int qt = gridDim.x - 1 - blockIdx.x;   // heavy (large-qt) blocks first
    const int q0 = qt * QB;
    const float scale = 0.08838834764831845f;    // 1/sqrt(128)

    // ---- load Q tile (scaled) ----
#pragma unroll
    for (int r = 0; r < 4; ++r) {
        const int f = tid + 256 * r;           // 0..1023
        const int row = f >> 5;                // 0..31
        const int c4 = (f & 31) << 2;          // 0..124
        float4 val = *(const float4*)&q[((size_t)(b * SEQ + q0 + row) * DMODEL) + h * HD + c4];
        Qs[row][c4 + 0] = val.x * scale;
        Qs[row][c4 + 1] = val.y * scale;
        Qs[row][c4 + 2] = val.z * scale;
        Qs[row][c4 + 3] = val.w * scale;
    }

    float m_r[2] = {-INFINITY, -INFINITY};
    float l_r[2] = {0.f, 0.f};
    float accO[2][2][4];
#pragma unroll
    for (int r = 0; r < 2; ++r)
#pragma unroll
        for (int sg = 0; sg < 2; ++sg)
#pragma unroll
            for (int cc = 0; cc < 4; ++cc) accO[r][sg][cc] = 0.f;

    for (int kt = 0; kt <= qt; ++kt) {
        const int k0 = kt * KB;
        __syncthreads();   // prior iteration done reading Ks/Vs/Ps
        // ---- load K,V tiles ----
#pragma unroll
        for (int r = 0; r < 4; ++r) {
            const int f = tid + 256 * r;
            const int row = f >> 5;
            const int c4 = (f & 31) << 2;
            const size_t g = ((size_t)(b * SEQ + k0 + row) * DMODEL) + h * HD + c4;
            float4 kv = *(const float4*)&k[g];
            Ks[row][c4 + 0] = kv.x; Ks[row][c4 + 1] = kv.y;
            Ks[row][c4 + 2] = kv.z; Ks[row][c4 + 3] = kv.w;
            float4 vv = *(const float4*)&v[g];
            Vs[row][c4 + 0] = vv.x; Vs[row][c4 + 1] = vv.y;
            Vs[row][c4 + 2] = vv.z; Vs[row][c4 + 3] = vv.w;
        }
        __syncthreads();

        // ---- scores: 2x2 per thread ----
        float s00 = 0.f, s01 = 0.f, s10 = 0.f, s11 = 0.f;
#pragma unroll 4
        for (int d = 0; d < HD; ++d) {
            const float qa = Qs[2 * ty + 0][d];
            const float qb2 = Qs[2 * ty + 1][d];
            const float ka = Ks[2 * tx + 0][d];
            const float kb2 = Ks[2 * tx + 1][d];
            s00 += qa * ka;  s01 += qa * kb2;
            s10 += qb2 * ka; s11 += qb2 * kb2;
        }
        // causal mask (same -1e9 additive value as reference)
        {
            const int qg0 = q0 + 2 * ty, qg1 = qg0 + 1;
            const int kg0 = k0 + 2 * tx, kg1 = kg0 + 1;
            if (kg0 > qg0) s00 = -1.0e9f;
            if (kg1 > qg0) s01 = -1.0e9f;
            if (kg0 > qg1) s10 = -1.0e9f;
            if (kg1 > qg1) s11 = -1.0e9f;
        }

        float tmax0 = fmaxf(s00, s01);
        float tmax1 = fmaxf(s10, s11);
#pragma unroll
        for (int msk = 1; msk <= 8; msk <<= 1) {
            tmax0 = fmaxf(tmax0, __shfl_xor(tmax0, msk, 64));
            tmax1 = fmaxf(tmax1, __shfl_xor(tmax1, msk, 64));
        }
        const float mn0 = fmaxf(m_r[0], tmax0);
        const float mn1 = fmaxf(m_r[1], tmax1);
        const float al0 = __expf(m_r[0] - mn0);
        const float al1 = __expf(m_r[1] - mn1);

        const float p00 = __expf(s00 - mn0);
        const float p01 = __expf(s01 - mn0);
        const float p10 = __expf(s10 - mn1);
        const float p11 = __expf(s11 - mn1);
        float ps0 = p00 + p01;
        float ps1 = p10 + p11;
#pragma unroll
        for (int msk = 1; msk <= 8; msk <<= 1) {
            ps0 += __shfl_xor(ps0, msk, 64);
            ps1 += __shfl_xor(ps1, msk, 64);
        }
        l_r[0] = l_r[0] * al0 + ps0;
        l_r[1] = l_r[1] * al1 + ps1;
        m_r[0] = mn0;
        m_r[1] = mn1;
#pragma unroll
        for (int sg = 0; sg < 2; ++sg)
#pragma unroll
            for (int cc = 0; cc < 4; ++cc) {
                accO[0][sg][cc] *= al0;
                accO[1][sg][cc] *= al1;
            }

        Ps[2 * ty + 0][2 * tx + 0] = p00;
        Ps[2 * ty + 0][2 * tx + 1] = p01;
        Ps[2 * ty + 1][2 * tx + 0] = p10;
        Ps[2 * ty + 1][2 * tx + 1] = p11;
        __syncthreads();

        // ---- PV: 2 rows x 8 cols per thread ----
#pragma unroll 4
        for (int j = 0; j < KB; ++j) {
            const float pa = Ps[2 * ty + 0][j];
            const float pb = Ps[2 * ty + 1][j];
            float4 v0 = *(const float4*)&Vs[j][4 * tx];
            float4 v1 = *(const float4*)&Vs[j][64 + 4 * tx];
            accO[0][0][0] += pa * v0.x; accO[0][0][1] += pa * v0.y;
            accO[0][0][2] += pa * v0.z; accO[0][0][3] += pa * v0.w;
            accO[0][1][0] += pa * v1.x; accO[0][1][1] += pa * v1.y;
            accO[0][1][2] += pa * v1.z; accO[0][1][3] += pa * v1.w;
            accO[1][0][0] += pb * v0.x; accO[1][0][1] += pb * v0.y;
            accO[1][0][2] += pb * v0.z; accO[1][0][3] += pb * v0.w;
            accO[1][1][0] += pb * v1.x; accO[1][1][1] += pb * v1.y;
            accO[1][1][2] += pb * v1.z; accO[1][1][3] += pb * v1.w;
        }
    }

    // ---- epilogue: normalize and store (layout (b,s,h*hd)) ----
#pragma unroll
    for (int r = 0; r < 2; ++r) {
        const float inv = 1.f / l_r[r];
        const size_t base = ((size_t)(b * SEQ + q0 + 2 * ty + r) * DMODEL) + h * HD;
        float4 o0 = make_float4(accO[r][0][0] * inv, accO[r][0][1] * inv,
                                accO[r][0][2] * inv, accO[r][0][3] * inv);
        float4 o1 = make_float4(accO[r][1][0] * inv, accO[r][1][1] * inv,
                                accO[r][1][2] * inv, accO[r][1][3] * inv);
        *(float4*)&o[base + 4 * tx] = o0;
        *(float4*)&o[base + 64 + 4 * tx] = o1;
    }
}

// =====================================================================
extern "C" void kernel_launch(void* const* d_in, const int* in_sizes, int n_in,
                              void* d_out, int out_size, void* d_ws, size_t ws_size,
                              hipStream_t stream) {
    const float* x  = (const float*)d_in[0];
    const float* wq = (const float*)d_in[1];
    const float* wk = (const float*)d_in[2];
    const float* wv = (const float*)d_in[3];
    const float* wo = (const float*)d_in[4];
    const float* fc = (const float*)d_in[5];
    const float* fs = (const float*)d_in[6];
    // d_in[7] = mask: not read; causal mask computed inline (same -1e9 value)
    float* out = (float*)d_out;

    const size_t elems = (size_t)BATCH * SEQ * DMODEL;  // 8.39M floats = 32 MB
    float* qb = (float*)d_ws;
    float* kb = qb + elems;
    float* vb = kb + elems;
    // attention output: separate region if workspace allows, else alias qb (safe)
    float* ab = (ws_size >= 4 * elems * sizeof(float)) ? (vb + elems) : qb;

    const int M = BATCH * SEQ;   // 4096
    const int N = DMODEL;        // 2048
    const int K = DMODEL;        // 2048
    dim3 gblk(N / 128, M / 128);

    gemm_nt<<<gblk, 256, 0, stream>>>(x, wq, qb, M, N, K);
    gemm_nt<<<gblk, 256, 0, stream>>>(x, wk, kb, M, N, K);
    gemm_nt<<<gblk, 256, 0, stream>>>(x, wv, vb, M, N, K);

    const long long npairs = (long long)BATCH * SEQ * DMODEL / 2;  // 4,194,304
    rope_kernel<<<dim3((unsigned)(npairs / 256), 2), 256, 0, stream>>>(qb, kb, fc, fs);

    attn_kernel<<<dim3(SEQ / QB, NH, BATCH), 256, 0, stream>>>(qb, kb, vb, ab);

    gemm_nt<<<gblk, 256, 0, stream>>>(ab, wo, out, M, N, K);
}

// Round 2
// 785.186 us; speedup vs baseline: 4.1172x; 4.1172x over previous
//
#include <hip/hip_runtime.h>
#include <math.h>

#define BATCH 2
#define SEQ 2048
#define DMODEL 2048
#define NH 16
#define HD 128

typedef __bf16 bf16x8 __attribute__((ext_vector_type(8)));
typedef __bf16 bf16x4 __attribute__((ext_vector_type(4)));
typedef float f32x4 __attribute__((ext_vector_type(4)));

// async global->LDS, 16B per lane; dst must be wave-uniform, HW adds lane*16
#define GLL16(dst, src)                                                          \
  __builtin_amdgcn_global_load_lds(                                              \
      (const __attribute__((address_space(1))) void*)(src),                      \
      (__attribute__((address_space(3))) void*)(dst), 16, 0, 0)

// =====================================================================
// split fp32 -> bf16 hi + bf16 lo  (hi = rne(v), lo = rne(v - hi))
// =====================================================================
__global__ __launch_bounds__(256) void split_fp32(const float* __restrict__ src,
                                                  __bf16* __restrict__ hi,
                                                  __bf16* __restrict__ lo) {
  const size_t i = (size_t)blockIdx.x * 256 + threadIdx.x;
  const float4 v = ((const float4*)src)[i];
  bf16x4 h, L;
  h[0] = (__bf16)v.x; h[1] = (__bf16)v.y; h[2] = (__bf16)v.z; h[3] = (__bf16)v.w;
  L[0] = (__bf16)(v.x - (float)h[0]);
  L[1] = (__bf16)(v.y - (float)h[1]);
  L[2] = (__bf16)(v.z - (float)h[2]);
  L[3] = (__bf16)(v.w - (float)h[3]);
  ((bf16x4*)hi)[i] = h;
  ((bf16x4*)lo)[i] = L;
}

// =====================================================================
// bf16x3 split GEMM (NT): C[M,N] = (Ah+Al)[M,K] . ((Bh+Bl)[N,K])^T
// 128x128 tile, BK=32, 4 waves, 16x16x32 MFMA, global_load_lds staging.
// EMIT: 0 = fp32 C, 1 = bf16 C.
// =====================================================================
template <int EMIT>
__global__ __launch_bounds__(256) void gemm_bs(const __bf16* __restrict__ Ah,
                                               const __bf16* __restrict__ Al,
                                               const __bf16* __restrict__ Bh,
                                               const __bf16* __restrict__ Bl,
                                               void* __restrict__ Cout,
                                               int M, int N, int K) {
  __shared__ __bf16 sAh[4096], sAl[4096], sBh[4096], sBl[4096];  // [128][32] each
  const int tid = threadIdx.x;
  const int l = tid & 63;
  const int w = tid >> 6;
  const int lg = l >> 4, lm = l & 15;
  const int wr = w >> 1, wc = w & 1;
  const int m0 = blockIdx.y * 128, n0 = blockIdx.x * 128;

  // staging: wave w issues insts {2w, 2w+1} per tile; lane -> row 16i+(l>>2), k-elems (l&3)*8
  const int sr = l >> 2;
  const int sc8 = (l & 3) * 8;
  const size_t rowA0 = (size_t)(m0 + 32 * w + sr);
  const size_t rowB0 = (size_t)(n0 + 32 * w + sr);

  f32x4 acc[4][4];
#pragma unroll
  for (int i = 0; i < 4; ++i)
#pragma unroll
    for (int j = 0; j < 4; ++j) { f32x4 z = {0.f, 0.f, 0.f, 0.f}; acc[i][j] = z; }

  for (int k0 = 0; k0 < K; k0 += 32) {
    __syncthreads();  // prior iteration's LDS reads done
    GLL16(sAh + 1024 * w,       Ah + rowA0 * K + k0 + sc8);
    GLL16(sAh + 1024 * w + 512, Ah + (rowA0 + 16) * K + k0 + sc8);
    GLL16(sAl + 1024 * w,       Al + rowA0 * K + k0 + sc8);
    GLL16(sAl + 1024 * w + 512, Al + (rowA0 + 16) * K + k0 + sc8);
    GLL16(sBh + 1024 * w,       Bh + rowB0 * K + k0 + sc8);
    GLL16(sBh + 1024 * w + 512, Bh + (rowB0 + 16) * K + k0 + sc8);
    GLL16(sBl + 1024 * w,       Bl + rowB0 * K + k0 + sc8);
    GLL16(sBl + 1024 * w + 512, Bl + (rowB0 + 16) * K + k0 + sc8);
    __syncthreads();  // drains vmcnt -> tiles ready

    bf16x8 fah[4], fal[4], fbh[4], fbl[4];
#pragma unroll
    for (int i = 0; i < 4; ++i) {
      const int ra = (wr * 64 + 16 * i + lm) * 32 + lg * 8;
      fah[i] = *(const bf16x8*)(sAh + ra);
      fal[i] = *(const bf16x8*)(sAl + ra);
      const int rb = (wc * 64 + 16 * i + lm) * 32 + lg * 8;
      fbh[i] = *(const bf16x8*)(sBh + rb);
      fbl[i] = *(const bf16x8*)(sBl + rb);
    }
#pragma unroll
    for (int i = 0; i < 4; ++i)
#pragma unroll
      for (int j = 0; j < 4; ++j) {
        acc[i][j] = __builtin_amdgcn_mfma_f32_16x16x32_bf16(fah[i], fbh[j], acc[i][j], 0, 0, 0);
        acc[i][j] = __builtin_amdgcn_mfma_f32_16x16x32_bf16(fah[i], fbl[j], acc[i][j], 0, 0, 0);
        acc[i][j] = __builtin_amdgcn_mfma_f32_16x16x32_bf16(fal[i], fbh[j], acc[i][j], 0, 0, 0);
      }
  }

#pragma unroll
  for (int i = 0; i < 4; ++i)
#pragma unroll
    for (int j = 0; j < 4; ++j)
#pragma unroll
      for (int r = 0; r < 4; ++r) {
        const size_t row = (size_t)(m0 + wr * 64 + 16 * i + lg * 4 + r);
        const size_t col = (size_t)(n0 + wc * 64 + 16 * j + lm);
        if (EMIT == 0) ((float*)Cout)[row * N + col] = acc[i][j][r];
        else           ((__bf16*)Cout)[row * N + col] = (__bf16)acc[i][j][r];
      }
}

// =====================================================================
// RoPE, in-place on bf16 tensor (b,s,h*hd); 4 elems (2 pairs) per thread.
// scale folds 1/sqrt(HD) into q.
// =====================================================================
__global__ __launch_bounds__(256) void rope_bf16(__bf16* __restrict__ t,
                                                 const float* __restrict__ cosp,
                                                 const float* __restrict__ sinp,
                                                 float scale) {
  const size_t i4 = (size_t)blockIdx.x * 256 + threadIdx.x;
  const size_t e = i4 * 4;
  const int srow = (int)((e >> 11) & 2047);  // token index s
  const int p = (int)(e & 127) >> 1;         // pair index (even), pairs p, p+1
  bf16x4 vv = *(bf16x4*)(t + e);
  const float c0 = cosp[srow * 64 + p],     s0 = sinp[srow * 64 + p];
  const float c1 = cosp[srow * 64 + p + 1], s1 = sinp[srow * 64 + p + 1];
  const float re0 = (float)vv[0], im0 = (float)vv[1];
  const float re1 = (float)vv[2], im1 = (float)vv[3];
  bf16x4 o;
  o[0] = (__bf16)((re0 * c0 - im0 * s0) * scale);
  o[1] = (__bf16)((re0 * s0 + im0 * c0) * scale);
  o[2] = (__bf16)((re1 * c1 - im1 * s1) * scale);
  o[3] = (__bf16)((re1 * s1 + im1 * c1) * scale);
  *(bf16x4*)(t + e) = o;
}

// =====================================================================
// bf16 MFMA flash attention, causal. Q-tile 64 (16 rows/wave), KV-tile 64.
// K in LDS padded stride 136 elems; V^T in LDS with XOR slot swizzle;
// P through per-wave LDS (padded stride 72). Output written split hi/lo.
// =====================================================================
__global__ __launch_bounds__(256) void attn_mfma(const __bf16* __restrict__ q,
                                                 const __bf16* __restrict__ k,
                                                 const __bf16* __restrict__ v,
                                                 __bf16* __restrict__ oh,
                                                 __bf16* __restrict__ ol) {
  __shared__ __bf16 Ks[64 * 136];                 // 17408 B, row stride 272 B
  __shared__ __align__(16) char Vt[128 * 144];    // 18432 B, V^T: elem (d,j) at d*144 + (2j ^ (((d>>3)&7)<<4))
  __shared__ __bf16 Ps[64 * 72];                  // 9216 B, row stride 144 B

  const int tid = threadIdx.x;
  const int l = tid & 63, w = tid >> 6;
  const int lg = l >> 4, lm = l & 15;
  const int b = blockIdx.z, h = blockIdx.y;
  const int qt = (int)gridDim.x - 1 - (int)blockIdx.x;  // heavy blocks first
  const int q0 = qt * 64;
  const size_t bh = (size_t)b * SEQ * DMODEL + (size_t)h * HD;

  // Q fragments in registers: wave w owns q-rows [q0+16w, +16)
  bf16x8 qf[4];
  {
    const __bf16* qr = q + bh + (size_t)(q0 + 16 * w + lm) * DMODEL;
#pragma unroll
    for (int c = 0; c < 4; ++c) qf[c] = *(const bf16x8*)(qr + c * 32 + lg * 8);
  }

  f32x4 accO[8];
#pragma unroll
  for (int dt = 0; dt < 8; ++dt) { f32x4 z = {0.f, 0.f, 0.f, 0.f}; accO[dt] = z; }
  float mrun[4] = {-1e30f, -1e30f, -1e30f, -1e30f};
  float lrun[4] = {0.f, 0.f, 0.f, 0.f};

  const int srT = tid >> 4;   // staging row group 0..15
  const int scT = tid & 15;   // staging 16B chunk

  for (int kt = 0; kt <= qt; ++kt) {
    const int k0 = kt * 64;
    __syncthreads();  // prior tile's K/V reads done
#pragma unroll
    for (int rnd = 0; rnd < 4; ++rnd) {
      const int r = srT + 16 * rnd;                      // kv row 0..63
      const size_t g = bh + (size_t)(k0 + r) * DMODEL + scT * 8;
      bf16x8 kv = *(const bf16x8*)(k + g);
      *(bf16x8*)(Ks + r * 136 + scT * 8) = kv;
      bf16x8 vv = *(const bf16x8*)(v + g);
      const int sw = (scT & 7) << 4;                     // == ((d>>3)&7)<<4 for d=scT*8+e
#pragma unroll
      for (int e = 0; e < 8; ++e) {
        const int d = scT * 8 + e;
        *(__bf16*)(Vt + d * 144 + ((2 * r) ^ sw)) = vv[e];
      }
    }
    __syncthreads();

    // ---- scores S = Q K^T (Q pre-scaled by 1/sqrt(HD) in rope) ----
    f32x4 sc[4];
#pragma unroll
    for (int nt = 0; nt < 4; ++nt) { f32x4 z = {0.f, 0.f, 0.f, 0.f}; sc[nt] = z; }
#pragma unroll
    for (int nt = 0; nt < 4; ++nt)
#pragma unroll
      for (int c = 0; c < 4; ++c) {
        bf16x8 kf = *(const bf16x8*)(Ks + (nt * 16 + lm) * 136 + c * 32 + lg * 8);
        sc[nt] = __builtin_amdgcn_mfma_f32_16x16x32_bf16(qf[c], kf, sc[nt], 0, 0, 0);
      }

    if (kt == qt) {  // diagonal tile: causal mask
      const int qg = q0 + 16 * w + lg * 4;
#pragma unroll
      for (int nt = 0; nt < 4; ++nt) {
        const int kg = k0 + nt * 16 + lm;
#pragma unroll
        for (int r = 0; r < 4; ++r)
          if (kg > qg + r) sc[nt][r] = -1e9f;
      }
    }

    // ---- online softmax (row = lg*4 + r, cols spread over 16 lanes x 4 nt) ----
    float alpha[4];
#pragma unroll
    for (int r = 0; r < 4; ++r) {
      float mx = fmaxf(fmaxf(sc[0][r], sc[1][r]), fmaxf(sc[2][r], sc[3][r]));
      mx = fmaxf(mx, __shfl_xor(mx, 1));
      mx = fmaxf(mx, __shfl_xor(mx, 2));
      mx = fmaxf(mx, __shfl_xor(mx, 4));
      mx = fmaxf(mx, __shfl_xor(mx, 8));
      const float mnew = fmaxf(mrun[r], mx);
      alpha[r] = __expf(mrun[r] - mnew);
      float rs = 0.f;
#pragma unroll
      for (int nt = 0; nt < 4; ++nt) {
        const float p = __expf(sc[nt][r] - mnew);
        sc[nt][r] = p;
        rs += p;
      }
      rs += __shfl_xor(rs, 1);
      rs += __shfl_xor(rs, 2);
      rs += __shfl_xor(rs, 4);
      rs += __shfl_xor(rs, 8);
      lrun[r] = lrun[r] * alpha[r] + rs;
      mrun[r] = mnew;
    }
#pragma unroll
    for (int dt = 0; dt < 8; ++dt)
#pragma unroll
      for (int r = 0; r < 4; ++r) accO[dt][r] *= alpha[r];

    // ---- P -> LDS (per-wave region, same-wave RAW: in-order LDS) ----
#pragma unroll
    for (int nt = 0; nt < 4; ++nt)
#pragma unroll
      for (int r = 0; r < 4; ++r)
        Ps[(16 * w + lg * 4 + r) * 72 + nt * 16 + lm] = (__bf16)sc[nt][r];

    bf16x8 pa0 = *(const bf16x8*)(Ps + (16 * w + lm) * 72 + lg * 8);
    bf16x8 pa1 = *(const bf16x8*)(Ps + (16 * w + lm) * 72 + 32 + lg * 8);
#pragma unroll
    for (int dt = 0; dt < 8; ++dt) {
      const int d = dt * 16 + lm;
      const int sw = ((d >> 3) & 7) << 4;
      bf16x8 v0 = *(const bf16x8*)(Vt + d * 144 + ((16 * lg) ^ sw));
      bf16x8 v1 = *(const bf16x8*)(Vt + d * 144 + ((64 + 16 * lg) ^ sw));
      accO[dt] = __builtin_amdgcn_mfma_f32_16x16x32_bf16(pa0, v0, accO[dt], 0, 0, 0);
      accO[dt] = __builtin_amdgcn_mfma_f32_16x16x32_bf16(pa1, v1, accO[dt], 0, 0, 0);
    }
  }

  // ---- epilogue: normalize, write split hi/lo bf16 ----
  float invl[4];
#pragma unroll
  for (int r = 0; r < 4; ++r) invl[r] = 1.f / lrun[r];
#pragma unroll
  for (int dt = 0; dt < 8; ++dt)
#pragma unroll
    for (int r = 0; r < 4; ++r) {
      const float val = accO[dt][r] * invl[r];
      const size_t oidx = bh + (size_t)(q0 + 16 * w + lg * 4 + r) * DMODEL + dt * 16 + lm;
      const __bf16 hv = (__bf16)val;
      oh[oidx] = hv;
      ol[oidx] = (__bf16)(val - (float)hv);
    }
}

// =====================================================================
extern "C" void kernel_launch(void* const* d_in, const int* in_sizes, int n_in,
                              void* d_out, int out_size, void* d_ws, size_t ws_size,
                              hipStream_t stream) {
  const float* x  = (const float*)d_in[0];
  const float* wq = (const float*)d_in[1];
  const float* wk = (const float*)d_in[2];
  const float* wv = (const float*)d_in[3];
  const float* wo = (const float*)d_in[4];
  const float* fc = (const float*)d_in[5];
  const float* fs = (const float*)d_in[6];
  // d_in[7] (mask) not read: causal mask applied inline with same -1e9 value.

  const size_t NTOK = (size_t)BATCH * SEQ;        // 4096
  const size_t NE   = NTOK * DMODEL;              // 8,388,608

  // workspace layout (64 MB total)
  char* wsb = (char*)d_ws;
  __bf16* xh = (__bf16*)wsb;                      // 16 MB
  __bf16* xl = xh + NE;                           // 16 MB
  __bf16* wh = (__bf16*)(wsb + 2 * NE * 2);       // 8 MB (reused per weight)
  __bf16* wl = wh + (size_t)DMODEL * DMODEL;      // 8 MB
  __bf16* vb = (__bf16*)(wsb + 2 * NE * 2 + 2 * (size_t)DMODEL * DMODEL * 2);  // 16 MB
  __bf16* oh = xh;                                // reuse x-split after QKV gemms
  __bf16* ol = xl;
  // bf16 Q/K live in d_out as scratch (dead before final gemm writes d_out)
  __bf16* qb = (__bf16*)d_out;
  __bf16* kb = qb + NE;

  const dim3 gg(DMODEL / 128, (unsigned)(NTOK / 128));  // (16, 32)
  const int sx = (int)(NE / 4 / 256);                    // 8192
  const int sw = DMODEL * DMODEL / 4 / 256;              // 4096

  split_fp32<<<sx, 256, 0, stream>>>(x, xh, xl);

  split_fp32<<<sw, 256, 0, stream>>>(wq, wh, wl);
  gemm_bs<1><<<gg, 256, 0, stream>>>(xh, xl, wh, wl, qb, (int)NTOK, DMODEL, DMODEL);
  split_fp32<<<sw, 256, 0, stream>>>(wk, wh, wl);
  gemm_bs<1><<<gg, 256, 0, stream>>>(xh, xl, wh, wl, kb, (int)NTOK, DMODEL, DMODEL);
  split_fp32<<<sw, 256, 0, stream>>>(wv, wh, wl);
  gemm_bs<1><<<gg, 256, 0, stream>>>(xh, xl, wh, wl, vb, (int)NTOK, DMODEL, DMODEL);

  rope_bf16<<<sx, 256, 0, stream>>>(qb, fc, fs, 0.08838834764831845f);  // 1/sqrt(128)
  rope_bf16<<<sx, 256, 0, stream>>>(kb, fc, fs, 1.0f);

  attn_mfma<<<dim3(SEQ / 64, NH, BATCH), 256, 0, stream>>>(qb, kb, vb, oh, ol);

  split_fp32<<<sw, 256, 0, stream>>>(wo, wh, wl);
  gemm_bs<0><<<gg, 256, 0, stream>>>(oh, ol, wh, wl, (float*)d_out, (int)NTOK, DMODEL, DMODEL);
}

// Round 5
// 670.005 us; speedup vs baseline: 4.8250x; 1.1719x over previous
//
#include <hip/hip_runtime.h>
#include <math.h>

#define BATCH 2
#define SEQ 2048
#define DMODEL 2048
#define NH 16
#define HD 128

typedef __bf16 bf16x8 __attribute__((ext_vector_type(8)));
typedef __bf16 bf16x4 __attribute__((ext_vector_type(4)));
typedef float f32x4 __attribute__((ext_vector_type(4)));
typedef float f32x16 __attribute__((ext_vector_type(16)));

// async global->LDS, 16B per lane; dst must be wave-uniform, HW adds lane*16
#define GLL16(dst, src)                                                          \
  __builtin_amdgcn_global_load_lds(                                              \
      (const __attribute__((address_space(1))) void*)(src),                      \
      (__attribute__((address_space(3))) void*)(dst), 16, 0, 0)

// =====================================================================
// split fp32 -> bf16 hi + bf16 lo  (hi = rne(v), lo = rne(v - hi))
// =====================================================================
__global__ __launch_bounds__(256) void split_fp32(const float* __restrict__ src,
                                                  __bf16* __restrict__ hi,
                                                  __bf16* __restrict__ lo) {
  const size_t i = (size_t)blockIdx.x * 256 + threadIdx.x;
  const float4 v = ((const float4*)src)[i];
  bf16x4 h, L;
  h[0] = (__bf16)v.x; h[1] = (__bf16)v.y; h[2] = (__bf16)v.z; h[3] = (__bf16)v.w;
  L[0] = (__bf16)(v.x - (float)h[0]);
  L[1] = (__bf16)(v.y - (float)h[1]);
  L[2] = (__bf16)(v.z - (float)h[2]);
  L[3] = (__bf16)(v.w - (float)h[3]);
  ((bf16x4*)hi)[i] = h;
  ((bf16x4*)lo)[i] = L;
}

// =====================================================================
// bf16x3 split GEMM (NT): C[M,N] = (Ah+Al)[M,K] . ((Bh+Bl)[N,K])^T
// 128x128 tile, BK=32, 4 waves, 16x16x32 MFMA, global_load_lds staging.
// EMIT: 0 = fp32 C, 1 = bf16 C.
// =====================================================================
template <int EMIT>
__global__ __launch_bounds__(256) void gemm_bs(const __bf16* __restrict__ Ah,
                                               const __bf16* __restrict__ Al,
                                               const __bf16* __restrict__ Bh,
                                               const __bf16* __restrict__ Bl,
                                               void* __restrict__ Cout,
                                               int M, int N, int K) {
  __shared__ __bf16 sAh[4096], sAl[4096], sBh[4096], sBl[4096];  // [128][32] each
  const int tid = threadIdx.x;
  const int l = tid & 63;
  const int w = tid >> 6;
  const int lg = l >> 4, lm = l & 15;
  const int wr = w >> 1, wc = w & 1;
  const int m0 = blockIdx.y * 128, n0 = blockIdx.x * 128;

  const int sr = l >> 2;
  const int sc8 = (l & 3) * 8;
  const size_t rowA0 = (size_t)(m0 + 32 * w + sr);
  const size_t rowB0 = (size_t)(n0 + 32 * w + sr);

  f32x4 acc[4][4];
#pragma unroll
  for (int i = 0; i < 4; ++i)
#pragma unroll
    for (int j = 0; j < 4; ++j) { f32x4 z = {0.f, 0.f, 0.f, 0.f}; acc[i][j] = z; }

  for (int k0 = 0; k0 < K; k0 += 32) {
    __syncthreads();
    GLL16(sAh + 1024 * w,       Ah + rowA0 * K + k0 + sc8);
    GLL16(sAh + 1024 * w + 512, Ah + (rowA0 + 16) * K + k0 + sc8);
    GLL16(sAl + 1024 * w,       Al + rowA0 * K + k0 + sc8);
    GLL16(sAl + 1024 * w + 512, Al + (rowA0 + 16) * K + k0 + sc8);
    GLL16(sBh + 1024 * w,       Bh + rowB0 * K + k0 + sc8);
    GLL16(sBh + 1024 * w + 512, Bh + (rowB0 + 16) * K + k0 + sc8);
    GLL16(sBl + 1024 * w,       Bl + rowB0 * K + k0 + sc8);
    GLL16(sBl + 1024 * w + 512, Bl + (rowB0 + 16) * K + k0 + sc8);
    __syncthreads();

    bf16x8 fah[4], fal[4], fbh[4], fbl[4];
#pragma unroll
    for (int i = 0; i < 4; ++i) {
      const int ra = (wr * 64 + 16 * i + lm) * 32 + lg * 8;
      fah[i] = *(const bf16x8*)(sAh + ra);
      fal[i] = *(const bf16x8*)(sAl + ra);
      const int rb = (wc * 64 + 16 * i + lm) * 32 + lg * 8;
      fbh[i] = *(const bf16x8*)(sBh + rb);
      fbl[i] = *(const bf16x8*)(sBl + rb);
    }
#pragma unroll
    for (int i = 0; i < 4; ++i)
#pragma unroll
      for (int j = 0; j < 4; ++j) {
        acc[i][j] = __builtin_amdgcn_mfma_f32_16x16x32_bf16(fah[i], fbh[j], acc[i][j], 0, 0, 0);
        acc[i][j] = __builtin_amdgcn_mfma_f32_16x16x32_bf16(fah[i], fbl[j], acc[i][j], 0, 0, 0);
        acc[i][j] = __builtin_amdgcn_mfma_f32_16x16x32_bf16(fal[i], fbh[j], acc[i][j], 0, 0, 0);
      }
  }

#pragma unroll
  for (int i = 0; i < 4; ++i)
#pragma unroll
    for (int j = 0; j < 4; ++j)
#pragma unroll
      for (int r = 0; r < 4; ++r) {
        const size_t row = (size_t)(m0 + wr * 64 + 16 * i + lg * 4 + r);
        const size_t col = (size_t)(n0 + wc * 64 + 16 * j + lm);
        if (EMIT == 0) ((float*)Cout)[row * N + col] = acc[i][j][r];
        else           ((__bf16*)Cout)[row * N + col] = (__bf16)acc[i][j][r];
      }
}

// =====================================================================
// RoPE, in-place on bf16 tensor (b,s,h*hd); 4 elems (2 pairs) per thread.
// =====================================================================
__global__ __launch_bounds__(256) void rope_bf16(__bf16* __restrict__ t,
                                                 const float* __restrict__ cosp,
                                                 const float* __restrict__ sinp,
                                                 float scale) {
  const size_t i4 = (size_t)blockIdx.x * 256 + threadIdx.x;
  const size_t e = i4 * 4;
  const int srow = (int)((e >> 11) & 2047);
  const int p = (int)(e & 127) >> 1;
  bf16x4 vv = *(bf16x4*)(t + e);
  const float c0 = cosp[srow * 64 + p],     s0 = sinp[srow * 64 + p];
  const float c1 = cosp[srow * 64 + p + 1], s1 = sinp[srow * 64 + p + 1];
  const float re0 = (float)vv[0], im0 = (float)vv[1];
  const float re1 = (float)vv[2], im1 = (float)vv[3];
  bf16x4 o;
  o[0] = (__bf16)((re0 * c0 - im0 * s0) * scale);
  o[1] = (__bf16)((re0 * s0 + im0 * c0) * scale);
  o[2] = (__bf16)((re1 * c1 - im1 * s1) * scale);
  o[3] = (__bf16)((re1 * s1 + im1 * c1) * scale);
  *(bf16x4*)(t + e) = o;
}

// pack two floats to one dword of 2 bf16 (low = a)
static __device__ __forceinline__ unsigned pk2(float a, float b) {
  unsigned short x = __builtin_bit_cast(unsigned short, (__bf16)a);
  unsigned short y = __builtin_bit_cast(unsigned short, (__bf16)b);
  return ((unsigned)y << 16) | (unsigned)x;
}

// =====================================================================
// Flash attention v2: 32x32x16 MFMA, swapped QK^T (S^T), in-register
// softmax + P, Q-tile 128 (4 waves x 32 q-rows), KV-tile 64.
// K in LDS stride 272B, V^T in LDS stride 144B, both XOR-block-swizzled
// (same XOR on write and read). Register prefetch of next K/V tile.
// XCD-aware block decode clusters one (b,h)'s q-blocks on one XCD.
// =====================================================================
__global__ __launch_bounds__(256) void attn_mfma2(const __bf16* __restrict__ q,
                                                  const __bf16* __restrict__ k,
                                                  const __bf16* __restrict__ v,
                                                  __bf16* __restrict__ oh,
                                                  __bf16* __restrict__ ol) {
  __shared__ __align__(16) char Ks[64 * 272];    // [kvrow][d], 16B pad, XOR swz
  __shared__ __align__(16) char Vt[128 * 144];   // [d][kvrow], 16B pad, XOR swz

  const int tid = threadIdx.x;
  const int l = tid & 63, w = tid >> 6;
  const int l31 = l & 31, hg = l >> 5;

  // block decode: f%8 = XCD slot; 4 (b,h) groups per XCD; heavy q-tiles first
  const int f = (int)blockIdx.x;
  const int X = f & 7, t = f >> 3;
  const int g = X * 4 + (t & 3);
  const int qt = 15 - (t >> 2);
  const int b = g >> 4, h = g & 15;
  const int q0 = qt * 128;
  const size_t bh = (size_t)b * SEQ * DMODEL + (size_t)h * HD;

  // Q fragments in registers: wave w owns q-rows [q0+32w, +32), lane -> row l31
  bf16x8 qf[8];
  {
    const __bf16* qr = q + bh + (size_t)(q0 + 32 * w + l31) * DMODEL;
#pragma unroll
    for (int ks = 0; ks < 8; ++ks) qf[ks] = *(const bf16x8*)(qr + ks * 16 + hg * 8);
  }

  f32x16 accO[4];
#pragma unroll
  for (int dt = 0; dt < 4; ++dt)
#pragma unroll
    for (int i = 0; i < 16; ++i) accO[dt][i] = 0.f;
  float m_own = -1e30f, l_own = 0.f;

  const int srT = tid >> 4;   // 0..15
  const int scT = tid & 15;   // 0..15
  const int nkt = 2 * qt + 2;
  const int qg_own = q0 + 32 * w + l31;     // this lane's q-row
  const int qg_min = q0 + 32 * w;           // wave's lowest q-row

  // register prefetch buffers
  bf16x8 kst[4], vst[4];
#pragma unroll
  for (int rnd = 0; rnd < 4; ++rnd) {
    const int r = srT + 16 * rnd;
    const size_t ga = bh + (size_t)(r) * DMODEL + scT * 8;
    kst[rnd] = *(const bf16x8*)(k + ga);
    vst[rnd] = *(const bf16x8*)(v + ga);
  }

  for (int kt = 0; kt < nkt; ++kt) {
    const int k0 = kt * 64;
    __syncthreads();   // previous tile's LDS reads done
    // ---- write staged tile to LDS (swizzled) ----
#pragma unroll
    for (int rnd = 0; rnd < 4; ++rnd) {
      const int r = srT + 16 * rnd;
      *(bf16x8*)(Ks + r * 272 + ((scT * 16) ^ (((r >> 3) & 7) << 4))) = kst[rnd];
      const int swz = (scT & 7) << 4;   // ((d>>3)&7)<<4 with d = scT*8+e
      const int cb = (2 * r) ^ swz;
#pragma unroll
      for (int e = 0; e < 8; ++e)
        *(__bf16*)(Vt + (scT * 8 + e) * 144 + cb) = vst[rnd][e];
    }
    __syncthreads();   // tile ready
    // ---- prefetch next tile into registers (overlaps compute) ----
    if (kt + 1 < nkt) {
#pragma unroll
      for (int rnd = 0; rnd < 4; ++rnd) {
        const int r = srT + 16 * rnd;
        const size_t ga = bh + (size_t)((kt + 1) * 64 + r) * DMODEL + scT * 8;
        kst[rnd] = *(const bf16x8*)(k + ga);
        vst[rnd] = *(const bf16x8*)(v + ga);
      }
    }
    if (k0 > qg_min + 31) continue;   // wave fully masked for this tile

    // ---- S^T = K Q^T : lane holds 32 k-rows for its q-col ----
    f32x16 sc[2];
#pragma unroll
    for (int mt = 0; mt < 2; ++mt)
#pragma unroll
      for (int i = 0; i < 16; ++i) sc[mt][i] = 0.f;
#pragma unroll
    for (int mt = 0; mt < 2; ++mt) {
      const int row = mt * 32 + l31;
      const char* kr = Ks + row * 272;
      const int sx = ((row >> 3) & 7) << 4;
#pragma unroll
      for (int ks = 0; ks < 8; ++ks) {
        bf16x8 kf = *(const bf16x8*)(kr + ((ks * 32 + hg * 16) ^ sx));
        sc[mt] = __builtin_amdgcn_mfma_f32_32x32x16_bf16(kf, qf[ks], sc[mt], 0, 0, 0);
      }
    }

    // ---- causal mask (boundary tiles only) ----
    if (k0 + 63 > qg_min) {
#pragma unroll
      for (int mt = 0; mt < 2; ++mt)
#pragma unroll
        for (int ri = 0; ri < 16; ++ri) {
          const int kg = k0 + mt * 32 + (ri & 3) + 8 * (ri >> 2) + 4 * hg;
          if (kg > qg_own) sc[mt][ri] = -INFINITY;
        }
    }

    // ---- online softmax: in-lane 32 + partner shfl ----
    float tm = -INFINITY;
#pragma unroll
    for (int mt = 0; mt < 2; ++mt)
#pragma unroll
      for (int ri = 0; ri < 16; ++ri) tm = fmaxf(tm, sc[mt][ri]);
    tm = fmaxf(tm, __shfl_xor(tm, 32));

    if (__any(tm > m_own)) {
      const float mnew = fmaxf(m_own, tm);
      const float alpha = __expf(m_own - mnew);
      m_own = mnew;
      l_own *= alpha;
#pragma unroll
      for (int ri = 0; ri < 16; ++ri) {
        const float a = __shfl(alpha, (ri & 3) + 8 * (ri >> 2) + 4 * hg);
#pragma unroll
        for (int dt = 0; dt < 4; ++dt) accO[dt][ri] *= a;
      }
    }
    float rs = 0.f;
#pragma unroll
    for (int mt = 0; mt < 2; ++mt)
#pragma unroll
      for (int ri = 0; ri < 16; ++ri) {
        const float p = __expf(sc[mt][ri] - m_own);
        sc[mt][ri] = p;
        rs += p;
      }
    rs += __shfl_xor(rs, 32);
    l_own += rs;

    // ---- PV: pack P (bf16) + partner exchange, 16 mfma ----
#pragma unroll
    for (int kk = 0; kk < 4; ++kk) {
      const int mt = kk >> 1, J8 = (kk & 1) * 8;
      unsigned oL0 = pk2(sc[mt][J8 + 0], sc[mt][J8 + 1]);
      unsigned oL1 = pk2(sc[mt][J8 + 2], sc[mt][J8 + 3]);
      unsigned oH0 = pk2(sc[mt][J8 + 4], sc[mt][J8 + 5]);
      unsigned oH1 = pk2(sc[mt][J8 + 6], sc[mt][J8 + 7]);
      // partner needs: hg0 sends H, hg1 sends L
      unsigned s0 = hg ? oL0 : oH0;
      unsigned s1 = hg ? oL1 : oH1;
      const unsigned r0 = (unsigned)__shfl_xor((int)s0, 32);
      const unsigned r1 = (unsigned)__shfl_xor((int)s1, 32);
      int4 fi;
      fi.x = (int)(hg ? r0 : oL0);
      fi.y = (int)(hg ? r1 : oL1);
      fi.z = (int)(hg ? oH0 : r0);
      fi.w = (int)(hg ? oH1 : r1);
      const bf16x8 pa = __builtin_bit_cast(bf16x8, fi);
      const int kb = (kk * 32 + hg * 16);
#pragma unroll
      for (int dt = 0; dt < 4; ++dt) {
        const int d = dt * 32 + l31;
        bf16x8 vf = *(const bf16x8*)(Vt + d * 144 + (kb ^ (((d >> 3) & 7) << 4)));
        accO[dt] = __builtin_amdgcn_mfma_f32_32x32x16_bf16(pa, vf, accO[dt], 0, 0, 0);
      }
    }
  }

  // ---- epilogue: normalize, split hi/lo bf16 store ----
  const float inv_own = 1.f / l_own;
#pragma unroll
  for (int ri = 0; ri < 16; ++ri) {
    const int row = (ri & 3) + 8 * (ri >> 2) + 4 * hg;
    const float il = __shfl(inv_own, row & 31);
    const size_t rbase = bh + (size_t)(q0 + 32 * w + row) * DMODEL;
#pragma unroll
    for (int dt = 0; dt < 4; ++dt) {
      const float val = accO[dt][ri] * il;
      const size_t idx = rbase + dt * 32 + l31;
      const __bf16 hv = (__bf16)val;
      oh[idx] = hv;
      ol[idx] = (__bf16)(val - (float)hv);
    }
  }
}

// =====================================================================
extern "C" void kernel_launch(void* const* d_in, const int* in_sizes, int n_in,
                              void* d_out, int out_size, void* d_ws, size_t ws_size,
                              hipStream_t stream) {
  const float* x  = (const float*)d_in[0];
  const float* wq = (const float*)d_in[1];
  const float* wk = (const float*)d_in[2];
  const float* wv = (const float*)d_in[3];
  const float* wo = (const float*)d_in[4];
  const float* fc = (const float*)d_in[5];
  const float* fs = (const float*)d_in[6];
  // d_in[7] (mask) not read: causal mask applied inline.

  const size_t NTOK = (size_t)BATCH * SEQ;        // 4096
  const size_t NE   = NTOK * DMODEL;              // 8,388,608

  char* wsb = (char*)d_ws;
  __bf16* xh = (__bf16*)wsb;
  __bf16* xl = xh + NE;
  __bf16* wh = (__bf16*)(wsb + 2 * NE * 2);
  __bf16* wl = wh + (size_t)DMODEL * DMODEL;
  __bf16* vb = (__bf16*)(wsb + 2 * NE * 2 + 2 * (size_t)DMODEL * DMODEL * 2);
  __bf16* oh = xh;                                // reuse x-split after QKV gemms
  __bf16* ol = xl;
  __bf16* qb = (__bf16*)d_out;                    // scratch in d_out
  __bf16* kb = qb + NE;

  const dim3 gg(DMODEL / 128, (unsigned)(NTOK / 128));
  const int sx = (int)(NE / 4 / 256);
  const int sw = DMODEL * DMODEL / 4 / 256;

  split_fp32<<<sx, 256, 0, stream>>>(x, xh, xl);

  split_fp32<<<sw, 256, 0, stream>>>(wq, wh, wl);
  gemm_bs<1><<<gg, 256, 0, stream>>>(xh, xl, wh, wl, qb, (int)NTOK, DMODEL, DMODEL);
  split_fp32<<<sw, 256, 0, stream>>>(wk, wh, wl);
  gemm_bs<1><<<gg, 256, 0, stream>>>(xh, xl, wh, wl, kb, (int)NTOK, DMODEL, DMODEL);
  split_fp32<<<sw, 256, 0, stream>>>(wv, wh, wl);
  gemm_bs<1><<<gg, 256, 0, stream>>>(xh, xl, wh, wl, vb, (int)NTOK, DMODEL, DMODEL);

  rope_bf16<<<sx, 256, 0, stream>>>(qb, fc, fs, 0.08838834764831845f);
  rope_bf16<<<sx, 256, 0, stream>>>(kb, fc, fs, 1.0f);

  // 512 blocks: 16 q-tiles x 16 heads x 2 batch, decoded XCD-aware in-kernel
  attn_mfma2<<<dim3(512), 256, 0, stream>>>(qb, kb, vb, oh, ol);

  split_fp32<<<sw, 256, 0, stream>>>(wo, wh, wl);
  gemm_bs<0><<<gg, 256, 0, stream>>>(oh, ol, wh, wl, (float*)d_out, (int)NTOK, DMODEL, DMODEL);
}